// Round 1
// baseline (45.340 us; speedup 1.0000x reference)
//
#include <hip/hip_runtime.h>

// CenterlineLoss: symmetric chamfer distance with in-bounds mask.
// proj: 16384 x 2 fp32, ref: 8192 x 2 fp32, scalar fp32 output.
// dist^2(i,j) = (p0_i - ref1_j)^2 + (p1_i - ref0_j)^2   (ref columns swapped)

constexpr int NP = 16384;   // proj points
constexpr int NR = 8192;    // ref points
constexpr int S1 = 16;      // ref-chunks for min1 kernel   (chunk = NR/S1 = 512)
constexpr int S2 = 32;      // proj-chunks for min2 kernel  (chunk = NP/S2 = 512)
constexpr int CHUNK = 512;
constexpr float FMAX = 3.4e38f;

// ---- K0: write masked proj (sentinel 1e15 for out-of-bounds points) ----
__global__ __launch_bounds__(256) void k_prep(const float* __restrict__ proj,
                                              float* __restrict__ pm) {
    int i = blockIdx.x * 256 + threadIdx.x;
    float px = proj[2 * i], py = proj[2 * i + 1];
    bool valid = (px >= 0.f) && (px <= 640.f) && (py >= 0.f) && (py <= 480.f);
    pm[2 * i]     = valid ? px : 1e15f;
    pm[2 * i + 1] = valid ? py : 1e15f;
}

// ---- K1: per proj point i, partial min over a 512-ref chunk ----
__global__ __launch_bounds__(256) void k_min1(const float* __restrict__ proj,
                                              const float* __restrict__ ref,
                                              float* __restrict__ min1p) {
    __shared__ float2 s[CHUNK];
    int tid = threadIdx.x;
    int i = blockIdx.x * 256 + tid;
    int c = blockIdx.y;
    // stage swapped ref chunk: s[p] = (ref_y, ref_x)
    float4 v = ((const float4*)(ref + 2 * c * CHUNK))[tid];
    s[2 * tid]     = make_float2(v.y, v.x);
    s[2 * tid + 1] = make_float2(v.w, v.z);
    __syncthreads();

    float2 p = ((const float2*)proj)[i];
    float m0 = FMAX, m1 = FMAX, m2 = FMAX, m3 = FMAX;
    for (int j = 0; j < CHUNK; j += 4) {
        float2 a = s[j], b = s[j + 1], cc = s[j + 2], d = s[j + 3];
        float dx0 = p.x - a.x,  dy0 = p.y - a.y;
        float dx1 = p.x - b.x,  dy1 = p.y - b.y;
        float dx2 = p.x - cc.x, dy2 = p.y - cc.y;
        float dx3 = p.x - d.x,  dy3 = p.y - d.y;
        m0 = fminf(m0, dx0 * dx0 + dy0 * dy0);
        m1 = fminf(m1, dx1 * dx1 + dy1 * dy1);
        m2 = fminf(m2, dx2 * dx2 + dy2 * dy2);
        m3 = fminf(m3, dx3 * dx3 + dy3 * dy3);
    }
    min1p[c * NP + i] = fminf(fminf(m0, m1), fminf(m2, m3));
}

// ---- K2: per ref point j, partial min over a 512-masked-proj chunk ----
__global__ __launch_bounds__(256) void k_min2(const float* __restrict__ ref,
                                              const float* __restrict__ pm,
                                              float* __restrict__ min2p) {
    __shared__ float2 s[CHUNK];
    int tid = threadIdx.x;
    int j = blockIdx.x * 256 + tid;
    int c = blockIdx.y;
    float4 v = ((const float4*)(pm + 2 * c * CHUNK))[tid];
    s[2 * tid]     = make_float2(v.x, v.y);
    s[2 * tid + 1] = make_float2(v.z, v.w);
    __syncthreads();

    float2 r = ((const float2*)ref)[j];
    float q0 = r.y, q1 = r.x;   // swapped ref columns
    float m0 = FMAX, m1 = FMAX, m2 = FMAX, m3 = FMAX;
    for (int i = 0; i < CHUNK; i += 4) {
        float2 a = s[i], b = s[i + 1], cc = s[i + 2], d = s[i + 3];
        float dx0 = a.x - q0,  dy0 = a.y - q1;
        float dx1 = b.x - q0,  dy1 = b.y - q1;
        float dx2 = cc.x - q0, dy2 = cc.y - q1;
        float dx3 = d.x - q0,  dy3 = d.y - q1;
        m0 = fminf(m0, dx0 * dx0 + dy0 * dy0);
        m1 = fminf(m1, dx1 * dx1 + dy1 * dy1);
        m2 = fminf(m2, dx2 * dx2 + dy2 * dy2);
        m3 = fminf(m3, dx3 * dx3 + dy3 * dy3);
    }
    min2p[c * NR + j] = fminf(fminf(m0, m1), fminf(m2, m3));
}

// ---- K3: combine partials; per-block deterministic tree-reduce sums ----
// blocks 0..63  : proj side -> bsum1[b], bcnt1[b]
// blocks 64..95 : ref side  -> bsum2[b-64]
__global__ __launch_bounds__(256) void k_combine(const float* __restrict__ proj,
                                                 const float* __restrict__ min1p,
                                                 const float* __restrict__ min2p,
                                                 float* __restrict__ bsum1,
                                                 float* __restrict__ bcnt1,
                                                 float* __restrict__ bsum2) {
    __shared__ float red[256];
    __shared__ float redc[256];
    int tid = threadIdx.x;
    int b = blockIdx.x;
    if (b < 64) {
        int i = b * 256 + tid;
        float m = FMAX;
        for (int ss = 0; ss < S1; ++ss) m = fminf(m, min1p[ss * NP + i]);
        float px = proj[2 * i], py = proj[2 * i + 1];
        bool valid = (px >= 0.f) && (px <= 640.f) && (py >= 0.f) && (py <= 480.f);
        red[tid]  = valid ? sqrtf(m) : 0.f;
        redc[tid] = valid ? 1.f : 0.f;
        __syncthreads();
        for (int w = 128; w > 0; w >>= 1) {
            if (tid < w) { red[tid] += red[tid + w]; redc[tid] += redc[tid + w]; }
            __syncthreads();
        }
        if (tid == 0) { bsum1[b] = red[0]; bcnt1[b] = redc[0]; }
    } else {
        int j = (b - 64) * 256 + tid;
        float m = FMAX;
        for (int ss = 0; ss < S2; ++ss) m = fminf(m, min2p[ss * NR + j]);
        red[tid] = sqrtf(m);
        __syncthreads();
        for (int w = 128; w > 0; w >>= 1) {
            if (tid < w) red[tid] += red[tid + w];
            __syncthreads();
        }
        if (tid == 0) bsum2[b - 64] = red[0];
    }
}

// ---- K4: final scalar, fixed summation order (fully deterministic) ----
__global__ void k_final(const float* __restrict__ bsum1,
                        const float* __restrict__ bcnt1,
                        const float* __restrict__ bsum2,
                        float* __restrict__ out) {
    float s1 = 0.f, c1 = 0.f, s2 = 0.f;
    for (int b = 0; b < 64; ++b) { s1 += bsum1[b]; c1 += bcnt1[b]; }
    for (int b = 0; b < 32; ++b) s2 += bsum2[b];
    out[0] = 0.5f * (s1 / c1 + s2 / (float)NR);
}

extern "C" void kernel_launch(void* const* d_in, const int* in_sizes, int n_in,
                              void* d_out, int out_size, void* d_ws, size_t ws_size,
                              hipStream_t stream) {
    const float* proj = (const float*)d_in[0];   // 16384 x 2
    const float* ref  = (const float*)d_in[1];   // 8192 x 2
    float* out = (float*)d_out;

    float* ws    = (float*)d_ws;
    float* pm    = ws;                    // 2*NP
    float* min1p = pm + 2 * NP;           // S1*NP
    float* min2p = min1p + S1 * NP;       // S2*NR
    float* bsum1 = min2p + S2 * NR;       // 64
    float* bcnt1 = bsum1 + 64;            // 64
    float* bsum2 = bcnt1 + 64;            // 32

    k_prep<<<NP / 256, 256, 0, stream>>>(proj, pm);
    k_min1<<<dim3(NP / 256, S1), 256, 0, stream>>>(proj, ref, min1p);
    k_min2<<<dim3(NR / 256, S2), 256, 0, stream>>>(ref, pm, min2p);
    k_combine<<<96, 256, 0, stream>>>(proj, min1p, min2p, bsum1, bcnt1, bsum2);
    k_final<<<1, 1, 0, stream>>>(bsum1, bcnt1, bsum2, out);
}